// Round 5
// baseline (18541.708 us; speedup 1.0000x reference)
//
#include <hip/hip_runtime.h>

typedef unsigned short u16;
typedef __attribute__((ext_vector_type(4))) float floatx4;
typedef __attribute__((ext_vector_type(8))) short short8;

#define B_SZ  128
#define L_SEQ 1024
#define V_SZ  32
#define E_SZ  256
#define H_SZ  1024

#define N_GROUPS     8      // batch groups of 16
#define WG_PER_GROUP 8      // 8 WGs x 128 cols = 1024
#define N_BLOCKS     (N_GROUPS * WG_PER_GROUP)   // 64 blocks: huge co-residency slack
#define LOGIT_BASE   (B_SZ * L_SEQ * V_SZ)       // hidden output offset in d_out

// workspace layout (bytes)
#define BAR_BYTES  8192
#define FLAG_OFF   (BAR_BYTES - 8)
#define P_OFF      BAR_BYTES
#define P_BYTES    (V_SZ * H_SZ * 4)             // 128 KB fp32: P = emb@We + bh
#define WOP_OFF    (P_OFF + P_BYTES)
#define WOP_BYTES  (H_SZ * V_SZ * 2)             // 64 KB: lane-packed Wo bf16 frags
#define HBUF_OFF   (WOP_OFF + WOP_BYTES)
#define HBUF_BYTES (N_GROUPS * 2 * 16 * H_SZ * 2)

#define MFMA16x16x32(a, b, c) __builtin_amdgcn_mfma_f32_16x16x32_bf16(a, b, c, 0, 0, 0)

__device__ inline float b2f(u16 u) {
    union { unsigned i; float f; } x; x.i = ((unsigned)u) << 16; return x.f;
}
__device__ inline u16 f2b(float f) {
    unsigned u = __float_as_uint(f);
    return (u16)((u + 0x7FFFu + ((u >> 16) & 1u)) >> 16);   // RNE
}
// dual-dtype loads (fp32 confirmed: R1 bf16-view NaN'd; keep detector, zero hot cost)
__device__ inline float ldf(const void* p, long i, int isf32) {
    return isf32 ? ((const float*)p)[i] : b2f(((const u16*)p)[i]);
}
__device__ inline u16 ldb(const void* p, long i, int isf32) {
    return isf32 ? f2b(((const float*)p)[i]) : ((const u16*)p)[i];
}

// ---------------------------------------------------------------------------
// dtype detectors. flag bit0: floats are fp32. flag bit1: x is int32.
// (R2==R4 bit-identity proved the detector resolves bit1=1 (int32) here.)
// ---------------------------------------------------------------------------
__global__ void detect_dtype(const u16* __restrict__ emb, const int* __restrict__ xi,
                             int* __restrict__ flag) {
    float v = b2f(emb[threadIdx.x]);
    if (!(fabsf(v) <= 1.0e6f)) atomicOr(flag, 1);
    if (xi[2 * threadIdx.x + 1] != 0) atomicOr(flag, 2);
}

// P[v][h] = sum_e emb[v][e]*We[e][h] + bh[h]  (fp32)
__global__ void precompute_P(const void* __restrict__ emb, const void* __restrict__ We,
                             const void* __restrict__ bh, float* __restrict__ P,
                             const int* __restrict__ flag) {
    const int isf32 = *flag & 1;
    int o = blockIdx.x * 256 + threadIdx.x;     // 32768
    int v = o >> 10, h = o & (H_SZ - 1);
    float acc = ldf(bh, h, isf32);
    for (int e = 0; e < E_SZ; ++e)
        acc += ldf(emb, v * E_SZ + e, isf32) * ldf(We, (long)e * H_SZ + h, isf32);
    P[o] = acc;
}

// Pack Wo into per-lane MFMA B-frag order: short8 index = vt*2048 + kc*64 + lane,
// element j: k = kc*32 + (lane>>4)*8 + j, v = vt*16 + (lane&15).
__global__ void pack_wo(const void* __restrict__ Wo, u16* __restrict__ pack,
                        const int* __restrict__ flag) {
    const int isf32 = *flag & 1;
    int idx = blockIdx.x * 256 + threadIdx.x;   // 32768
    int j = idx & 7, lane = (idx >> 3) & 63, kc = (idx >> 9) & 31, vt = idx >> 14;
    int k = kc * 32 + (lane >> 4) * 8 + j;
    int v = vt * 16 + (lane & 15);
    pack[idx] = ldb(Wo, (long)k * V_SZ + v, isf32);
}

// ---------------------------------------------------------------------------
// group barrier: monotonic counter, agent-scope (cross-XCD correct).
// ---------------------------------------------------------------------------
__device__ inline void group_barrier(unsigned* bar, unsigned idx) {
    __builtin_amdgcn_s_waitcnt(0);
    __syncthreads();
    if (threadIdx.x == 0) {
        __builtin_amdgcn_fence(__ATOMIC_RELEASE, "agent");
        __hip_atomic_fetch_add(bar, 1u, __ATOMIC_RELAXED, __HIP_MEMORY_SCOPE_AGENT);
        unsigned target = idx * (unsigned)WG_PER_GROUP;
        long guard = 0;
        while (__hip_atomic_load(bar, __ATOMIC_RELAXED, __HIP_MEMORY_SCOPE_AGENT) < target) {
            __builtin_amdgcn_s_sleep(1);
            if (++guard > 20000000L) break;  // fail visibly, never hang
        }
    }
    __syncthreads();
    __builtin_amdgcn_fence(__ATOMIC_ACQUIRE, "agent");
}

// ---------------------------------------------------------------------------
// Persistent RNN. 64 blocks x 1024 thr. group g = blockIdx&7 (16 batches),
// wg = blockIdx>>3 owns W_h cols [128*wg, 128*wg+128) in VGPRs.
// wave wv: ntile = wv>>1 (16-col tile), khalf = wv&1 (K half, 512 each);
// 16 MFMAs accumulate in-register; 2-way LDS reduce across khalf.
// WG0 waves with ntile<2 also compute logits (Wo frags from packed L2 buffer).
// OUTPUT IS FP32 (R4 post-mortem: u16 stores aliased hidden into logit region).
// ---------------------------------------------------------------------------
__global__ void __launch_bounds__(1024) rnn_kernel(
    const void* __restrict__ xp, const void* __restrict__ hidden,
    const void* __restrict__ Wh, const u16* __restrict__ wopack,
    const void* __restrict__ bo, const float* __restrict__ P,
    unsigned* __restrict__ bars, u16* __restrict__ hbuf, float* __restrict__ out,
    const int* __restrict__ flag)
{
    __shared__ float red[5120];   // 4096 h-partials + 1024 logit-partials (20KB)

    const int fl    = *flag;
    const int isf32 = fl & 1;
    const int xi64  = !(fl & 2);         // x delivered as int64?
    const int g     = blockIdx.x & 7;
    const int wg    = blockIdx.x >> 3;
    const int col0  = wg * 128;
    const int b0    = g * 16;
    const int tid   = threadIdx.x;
    const int wv    = tid >> 6;          // 0..15
    const int lane  = tid & 63;
    const int lrow  = lane & 15;
    const int quad  = lane >> 4;
    const int ntile = wv >> 1;           // 0..7 (16-col tile within this WG)
    const int khalf = wv & 1;            // K in [khalf*512, khalf*512+512)
    const int k0    = khalf * 512;
    const bool do_logit = (wg == 0) && (ntile < 2);

    const int* x32       = (const int*)xp;
    const long long* x64 = (const long long*)xp;

    unsigned* bar = bars + g * 256;
    u16* hb0 = hbuf + g * (2 * 16 * H_SZ);
    u16* hb1 = hb0 + 16 * H_SZ;

    // ---- stationary Wh fragments: B[k][n], k = k0+kk*32+quad*8+j, n = col ----
    short8 whf[16];
    const int coln = col0 + ntile * 16 + lrow;
    #pragma unroll
    for (int kk = 0; kk < 16; ++kk) {
        const int kb = k0 + kk * 32 + quad * 8;
        #pragma unroll
        for (int j = 0; j < 8; ++j)
            whf[kk][j] = (short)ldb(Wh, (long)(kb + j) * H_SZ + coln, isf32);
    }
    // packed Wo frag pointer (only meaningful for logit waves)
    const short8* wop = (const short8*)wopack + ((ntile * 32 + khalf * 16) * 64 + lane);
    const float bov = ldf(bo, tid & 31, isf32);

    // ---- init h_0 slice ----
    for (int i = tid; i < 16 * 128; i += 1024) {
        int b = i >> 7, c = i & 127;
        hb0[b * H_SZ + col0 + c] = ldb(hidden, (long)(b0 + b) * H_SZ + col0 + c, isf32);
    }
    group_barrier(bar, 1u);

    for (int s = 0; s < L_SEQ; ++s) {
        const u16* hc = (s & 1) ? hb1 : hb0;
        u16*       hn = (s & 1) ? hb0 : hb1;

        floatx4 acc  = {0, 0, 0, 0};
        floatx4 accL = {0, 0, 0, 0};
        const u16* arow = hc + lrow * H_SZ + k0 + quad * 8;
        #pragma unroll
        for (int kk = 0; kk < 16; ++kk) {
            short8 a = *(const short8*)(arow + kk * 32);
            acc = MFMA16x16x32(a, whf[kk], acc);
            if (do_logit) accL = MFMA16x16x32(a, wop[kk * 64], accL);
        }
        // C layout: col = lane&15, row = quad*4 + r
        #pragma unroll
        for (int r = 0; r < 4; ++r) {
            int m = quad * 4 + r;
            red[(ntile * 256 + m * 16 + lrow) * 2 + khalf] = acc[r];
            if (do_logit)
                red[4096 + (ntile * 256 + m * 16 + lrow) * 2 + khalf] = accL[r];
        }
        __syncthreads();

        // ---- epilogue: h_{s+1} = tanh(P[x_s] + h_s @ Wh) ----
        #pragma unroll
        for (int i0 = 0; i0 < 2; ++i0) {
            int i = tid + i0 * 1024;            // 2048 = 16 batches x 128 cols
            int b = i >> 7, c = i & 127;
            const float* rp = &red[((c >> 4) * 256 + b * 16 + (c & 15)) * 2];
            float sum = rp[0] + rp[1];
            long xoff = (long)(b0 + b) * L_SEQ + s;
            int xv = xi64 ? (int)x64[xoff] : x32[xoff];
            float h = tanhf(sum + P[xv * H_SZ + col0 + c]);
            hn[b * H_SZ + col0 + c] = f2b(h);
            if (s == L_SEQ - 1)
                out[LOGIT_BASE + (b0 + b) * H_SZ + col0 + c] = h;   // fp32 store
        }
        // ---- WG0: logits[t=s-1] = h_s @ Wo + bo (fp32 store) ----
        if (wg == 0 && s >= 1 && tid < 512) {
            int b = tid >> 5, v = tid & 31;
            const float* rp = &red[4096 + ((v >> 4) * 256 + b * 16 + (v & 15)) * 2];
            out[((b0 + b) * L_SEQ + (s - 1)) * V_SZ + v] = rp[0] + rp[1] + bov;
        }
        group_barrier(bar, (unsigned)(s + 2));
    }

    // ---- final logits t = L-1 from h_L (hb0: L even) ----
    if (wg == 0) {
        if (ntile < 2) {
            floatx4 accL = {0, 0, 0, 0};
            const u16* arow = hb0 + lrow * H_SZ + k0 + quad * 8;
            #pragma unroll
            for (int kk = 0; kk < 16; ++kk)
                accL = MFMA16x16x32(*(const short8*)(arow + kk * 32), wop[kk * 64], accL);
            #pragma unroll
            for (int r = 0; r < 4; ++r)
                red[4096 + (ntile * 256 + (quad * 4 + r) * 16 + lrow) * 2 + khalf] = accL[r];
        }
        __syncthreads();
        if (tid < 512) {
            int b = tid >> 5, v = tid & 31;
            const float* rp = &red[4096 + ((v >> 4) * 256 + b * 16 + (v & 15)) * 2];
            out[((b0 + b) * L_SEQ + (L_SEQ - 1)) * V_SZ + v] = rp[0] + rp[1] + bov;
        }
    }
}

// ---------------------------------------------------------------------------
extern "C" void kernel_launch(void* const* d_in, const int* in_sizes, int n_in,
                              void* d_out, int out_size, void* d_ws, size_t ws_size,
                              hipStream_t stream) {
    (void)in_sizes; (void)n_in; (void)out_size; (void)ws_size;
    const void* x      = d_in[0];   // int32 (runtime-verified)
    const void* hidden = d_in[1];
    const void* emb    = d_in[2];
    const void* We     = d_in[3];
    const void* Wh     = d_in[4];
    const void* bh     = d_in[5];
    const void* Wo     = d_in[6];
    const void* bo     = d_in[7];
    float* out = (float*)d_out;     // fp32 (R4 post-mortem)

    char* ws = (char*)d_ws;
    unsigned* bars = (unsigned*)ws;
    int*   flag   = (int*)(ws + FLAG_OFF);
    float* P      = (float*)(ws + P_OFF);
    u16*   wopack = (u16*)(ws + WOP_OFF);
    u16*   hbuf   = (u16*)(ws + HBUF_OFF);

    hipMemsetAsync(ws, 0, BAR_BYTES, stream);   // zero barrier counters + flags

    detect_dtype<<<dim3(1), dim3(256), 0, stream>>>((const u16*)emb, (const int*)x, flag);
    precompute_P<<<dim3(128), dim3(256), 0, stream>>>(emb, We, bh, P, flag);
    pack_wo<<<dim3(128), dim3(256), 0, stream>>>(Wo, wopack, flag);

    rnn_kernel<<<dim3(N_BLOCKS), dim3(1024), 0, stream>>>(
        x, hidden, Wh, wopack, bo, P, bars, hbuf, out, flag);
}

// Round 6
// 5614.897 us; speedup vs baseline: 3.3022x; 3.3022x over previous
//
#include <hip/hip_runtime.h>

typedef unsigned short u16;
typedef unsigned int   u32;
typedef __attribute__((ext_vector_type(4))) float floatx4;
typedef __attribute__((ext_vector_type(8))) short short8;

#define B_SZ  128
#define L_SEQ 1024
#define V_SZ  32
#define E_SZ  256
#define H_SZ  1024

#define N_GROUPS     8      // batch groups of 16
#define WG_PER_GROUP 32     // 32 WGs x 32 cols = 1024
#define N_BLOCKS     (N_GROUPS * WG_PER_GROUP)   // 256 WGs x 4 waves: capacity-safe
#define LOGIT_BASE   (B_SZ * L_SEQ * V_SZ)

// workspace layout (bytes)
#define BAR_BYTES  8192
#define FLAG_OFF   (BAR_BYTES - 8)
#define P_OFF      BAR_BYTES
#define P_BYTES    (V_SZ * H_SZ * 4)
#define HBUF_OFF   (P_OFF + P_BYTES)
#define HBUF_BYTES (N_GROUPS * 2 * 16 * H_SZ * 2)

#define MFMA16x16x32(a, b, c) __builtin_amdgcn_mfma_f32_16x16x32_bf16(a, b, c, 0, 0, 0)

__device__ inline float b2f(u16 u) {
    union { unsigned i; float f; } x; x.i = ((unsigned)u) << 16; return x.f;
}
__device__ inline u16 f2b(float f) {
    unsigned u = __float_as_uint(f);
    return (u16)((u + 0x7FFFu + ((u >> 16) & 1u)) >> 16);   // RNE
}
__device__ inline float ldf(const void* p, long i, int isf32) {
    return isf32 ? ((const float*)p)[i] : b2f(((const u16*)p)[i]);
}
__device__ inline u16 ldb(const void* p, long i, int isf32) {
    return isf32 ? f2b(((const float*)p)[i]) : ((const u16*)p)[i];
}

// HW-coherent h exchange: relaxed agent-scope atomics compile to sc1
// global loads/stores that bypass the non-coherent per-XCD L2 and are
// coherent at LLC. NO cache-wide fences needed (R5 post-mortem: agent
// fences = per-step L2 wbinv = the 18 us/step).
__device__ inline u32 cload(const u32* p) {
    return __hip_atomic_load((u32*)p, __ATOMIC_RELAXED, __HIP_MEMORY_SCOPE_AGENT);
}
__device__ inline void cstore(u32* p, u32 v) {
    __hip_atomic_store(p, v, __ATOMIC_RELAXED, __HIP_MEMORY_SCOPE_AGENT);
}

// ---------------------------------------------------------------------------
// dtype detectors. bit0: floats are fp32. bit1: x is int32. (both confirmed
// by R1-R5 evidence; kept as zero-hot-cost insurance.)
__global__ void detect_dtype(const u16* __restrict__ emb, const int* __restrict__ xi,
                             int* __restrict__ flag) {
    float v = b2f(emb[threadIdx.x]);
    if (!(fabsf(v) <= 1.0e6f)) atomicOr(flag, 1);
    if (xi[2 * threadIdx.x + 1] != 0) atomicOr(flag, 2);
}

// P[v][h] = sum_e emb[v][e]*We[e][h] + bh[h]  (fp32)
__global__ void precompute_P(const void* __restrict__ emb, const void* __restrict__ We,
                             const void* __restrict__ bh, float* __restrict__ P,
                             const int* __restrict__ flag) {
    const int isf32 = *flag & 1;
    int o = blockIdx.x * 256 + threadIdx.x;
    int v = o >> 10, h = o & (H_SZ - 1);
    float acc = ldf(bh, h, isf32);
    for (int e = 0; e < E_SZ; ++e)
        acc += ldf(emb, v * E_SZ + e, isf32) * ldf(We, (long)e * H_SZ + h, isf32);
    P[o] = acc;
}

// ---------------------------------------------------------------------------
// Fence-free group barrier: s_waitcnt(0) drains this WG's sc1 stores to the
// coherence point; relaxed atomicAdd + relaxed poll; no wbl2/inv anywhere.
// ---------------------------------------------------------------------------
__device__ inline void group_barrier(unsigned* bar, unsigned idx) {
    __builtin_amdgcn_s_waitcnt(0);
    __syncthreads();
    if (threadIdx.x == 0) {
        __hip_atomic_fetch_add(bar, 1u, __ATOMIC_RELAXED, __HIP_MEMORY_SCOPE_AGENT);
        unsigned target = idx * (unsigned)WG_PER_GROUP;
        long guard = 0;
        while (__hip_atomic_load(bar, __ATOMIC_RELAXED, __HIP_MEMORY_SCOPE_AGENT) < target) {
            __builtin_amdgcn_s_sleep(2);
            if (++guard > 1000000L) break;   // fail visibly, never hang
        }
    }
    __syncthreads();
}

// ---------------------------------------------------------------------------
// Persistent RNN. 256 WGs x 256 thr (4 waves). group g = blockIdx&7
// (16 batches), wg = blockIdx>>3 owns W_h cols [32wg, 32wg+32) stationary in
// VGPRs (whf: 64 VGPRs; launch_bounds(256,1) -> 512 VGPR budget, no spill).
// Wave w owns K quarter [256w, 256w+256): 8 frags, 16 MFMAs, 4-way LDS reduce.
// Logit duty rotates: WG (s%32) computes logits[s-1] = h_s @ Wo + bo using
// the same A-frags (wof resident in all WGs).
// ---------------------------------------------------------------------------
__global__ void __launch_bounds__(256, 1) rnn_kernel(
    const void* __restrict__ xp, const void* __restrict__ hidden,
    const void* __restrict__ Wh, const void* __restrict__ Wo,
    const void* __restrict__ bo, const float* __restrict__ P,
    unsigned* __restrict__ bars, u16* __restrict__ hbuf, float* __restrict__ out,
    const int* __restrict__ flag)
{
    __shared__ float red[4096];   // [0,2048): h partials; [2048,4096): logit partials

    const int fl    = *flag;
    const int isf32 = fl & 1;
    const int xi64  = !(fl & 2);
    const int g     = blockIdx.x & 7;
    const int wg    = blockIdx.x >> 3;
    const int col0  = wg * 32;
    const int b0    = g * 16;
    const int tid   = threadIdx.x;
    const int wave  = tid >> 6;
    const int lane  = tid & 63;
    const int lrow  = lane & 15;
    const int quad  = lane >> 4;
    const int kwave = wave * 256;

    const int* x32       = (const int*)xp;
    const long long* x64 = (const long long*)xp;

    unsigned* bar = bars + g * 256;
    u16* hb0 = hbuf + g * (2 * 16 * H_SZ);
    u16* hb1 = hb0 + 16 * H_SZ;

    // ---- stationary weight fragments (normal cached loads, L2-warm forever) ----
    short8 whf[2][8], wof[2][8];
    #pragma unroll
    for (int kk = 0; kk < 8; ++kk) {
        const int kb = kwave + kk * 32 + quad * 8;
        #pragma unroll
        for (int j = 0; j < 8; ++j) {
            whf[0][kk][j] = (short)ldb(Wh, (long)(kb + j) * H_SZ + col0 + lrow, isf32);
            whf[1][kk][j] = (short)ldb(Wh, (long)(kb + j) * H_SZ + col0 + 16 + lrow, isf32);
            wof[0][kk][j] = (short)ldb(Wo, (long)(kb + j) * V_SZ + lrow, isf32);
            wof[1][kk][j] = (short)ldb(Wo, (long)(kb + j) * V_SZ + 16 + lrow, isf32);
        }
    }

    const int bq = tid >> 4;             // batch row 0..15
    const int cp = (tid & 15) * 2;       // even col/vocab pair base 0..30
    const float bov0 = ldf(bo, cp, isf32);
    const float bov1 = ldf(bo, cp + 1, isf32);

    // ---- init h_0 slice (coherent u32 stores) ----
    {
        u16 lo = ldb(hidden, (long)(b0 + bq) * H_SZ + col0 + cp, isf32);
        u16 hi = ldb(hidden, (long)(b0 + bq) * H_SZ + col0 + cp + 1, isf32);
        cstore((u32*)hb0 + ((bq * H_SZ + col0 + cp) >> 1), (u32)lo | ((u32)hi << 16));
    }
    group_barrier(bar, 1u);

    for (int s = 0; s < L_SEQ; ++s) {
        const u16* hc = (s & 1) ? hb1 : hb0;
        u16*       hn = (s & 1) ? hb0 : hb1;
        const bool do_logit = (wg == (s & 31));

        floatx4 acc0 = {0,0,0,0}, acc1 = {0,0,0,0};
        floatx4 aL0  = {0,0,0,0}, aL1  = {0,0,0,0};
        const u32* aw = (const u32*)hc + ((lrow * H_SZ + kwave + quad * 8) >> 1);
        #pragma unroll
        for (int kk = 0; kk < 8; ++kk) {
            union { short8 s8; u32 u[4]; } af;
            const u32* p = aw + kk * 16;
            af.u[0] = cload(p);     af.u[1] = cload(p + 1);
            af.u[2] = cload(p + 2); af.u[3] = cload(p + 3);
            acc0 = MFMA16x16x32(af.s8, whf[0][kk], acc0);
            acc1 = MFMA16x16x32(af.s8, whf[1][kk], acc1);
            if (do_logit) {
                aL0 = MFMA16x16x32(af.s8, wof[0][kk], aL0);
                aL1 = MFMA16x16x32(af.s8, wof[1][kk], aL1);
            }
        }
        // C layout: col = lane&15, row = quad*4 + r
        #pragma unroll
        for (int r = 0; r < 4; ++r) {
            int m = quad * 4 + r;
            red[(m * 16 + lrow) * 4 + wave]         = acc0[r];
            red[(256 + m * 16 + lrow) * 4 + wave]   = acc1[r];
            if (do_logit) {
                red[2048 + (m * 16 + lrow) * 4 + wave]       = aL0[r];
                red[2048 + (256 + m * 16 + lrow) * 4 + wave] = aL1[r];
            }
        }
        __syncthreads();

        // ---- epilogue: h_{s+1} = tanh(P[x_s] + h_s @ Wh), 2 cols/thread ----
        {
            int nt = cp >> 4, cc = cp & 15;
            const float* rp = &red[(nt * 256 + bq * 16 + cc) * 4];
            float s0 = rp[0] + rp[1] + rp[2] + rp[3];
            float s1 = rp[4] + rp[5] + rp[6] + rp[7];
            long xoff = (long)(b0 + bq) * L_SEQ + s;
            int xv = xi64 ? (int)x64[xoff] : x32[xoff];
            float h0 = tanhf(s0 + P[xv * H_SZ + col0 + cp]);
            float h1 = tanhf(s1 + P[xv * H_SZ + col0 + cp + 1]);
            cstore((u32*)hn + ((bq * H_SZ + col0 + cp) >> 1),
                   (u32)f2b(h0) | ((u32)f2b(h1) << 16));
            if (s == L_SEQ - 1) {
                out[LOGIT_BASE + (b0 + bq) * H_SZ + col0 + cp]     = h0;
                out[LOGIT_BASE + (b0 + bq) * H_SZ + col0 + cp + 1] = h1;
            }
        }
        // ---- rotating WG: logits[t=s-1] = h_s @ Wo + bo ----
        if (do_logit && s >= 1) {
            int nt = cp >> 4, cc = cp & 15;
            const float* rp = &red[2048 + (nt * 256 + bq * 16 + cc) * 4];
            long ob = ((long)(b0 + bq) * L_SEQ + (s - 1)) * V_SZ + cp;
            out[ob]     = rp[0] + rp[1] + rp[2] + rp[3] + bov0;
            out[ob + 1] = rp[4] + rp[5] + rp[6] + rp[7] + bov1;
        }
        group_barrier(bar, (unsigned)(s + 2));
    }

    // ---- final logits t = L-1 from h_L (in hb0: L even), WG0 ----
    if (wg == 0) {
        floatx4 aL0 = {0,0,0,0}, aL1 = {0,0,0,0};
        const u32* aw = (const u32*)hb0 + ((lrow * H_SZ + kwave + quad * 8) >> 1);
        #pragma unroll
        for (int kk = 0; kk < 8; ++kk) {
            union { short8 s8; u32 u[4]; } af;
            const u32* p = aw + kk * 16;
            af.u[0] = cload(p);     af.u[1] = cload(p + 1);
            af.u[2] = cload(p + 2); af.u[3] = cload(p + 3);
            aL0 = MFMA16x16x32(af.s8, wof[0][kk], aL0);
            aL1 = MFMA16x16x32(af.s8, wof[1][kk], aL1);
        }
        #pragma unroll
        for (int r = 0; r < 4; ++r) {
            int m = quad * 4 + r;
            red[2048 + (m * 16 + lrow) * 4 + wave]       = aL0[r];
            red[2048 + (256 + m * 16 + lrow) * 4 + wave] = aL1[r];
        }
        __syncthreads();
        {
            int nt = cp >> 4, cc = cp & 15;
            const float* rp = &red[2048 + (nt * 256 + bq * 16 + cc) * 4];
            long ob = ((long)(b0 + bq) * L_SEQ + (L_SEQ - 1)) * V_SZ + cp;
            out[ob]     = rp[0] + rp[1] + rp[2] + rp[3] + bov0;
            out[ob + 1] = rp[4] + rp[5] + rp[6] + rp[7] + bov1;
        }
    }
}

// ---------------------------------------------------------------------------
extern "C" void kernel_launch(void* const* d_in, const int* in_sizes, int n_in,
                              void* d_out, int out_size, void* d_ws, size_t ws_size,
                              hipStream_t stream) {
    (void)in_sizes; (void)n_in; (void)out_size; (void)ws_size;
    const void* x      = d_in[0];   // int32 (runtime-verified)
    const void* hidden = d_in[1];
    const void* emb    = d_in[2];
    const void* We     = d_in[3];
    const void* Wh     = d_in[4];
    const void* bh     = d_in[5];
    const void* Wo     = d_in[6];
    const void* bo     = d_in[7];
    float* out = (float*)d_out;     // fp32 (R4 post-mortem)

    char* ws = (char*)d_ws;
    unsigned* bars = (unsigned*)ws;
    int*   flag = (int*)(ws + FLAG_OFF);
    float* P    = (float*)(ws + P_OFF);
    u16*   hbuf = (u16*)(ws + HBUF_OFF);

    hipMemsetAsync(ws, 0, BAR_BYTES, stream);   // zero barrier counters + flags

    detect_dtype<<<dim3(1), dim3(256), 0, stream>>>((const u16*)emb, (const int*)x, flag);
    precompute_P<<<dim3(128), dim3(256), 0, stream>>>(emb, We, bh, P, flag);

    rnn_kernel<<<dim3(N_BLOCKS), dim3(256), 0, stream>>>(
        x, hidden, Wh, Wo, bo, P, bars, hbuf, out, flag);
}